// Round 5
// baseline (164.856 us; speedup 1.0000x reference)
//
#include <hip/hip_runtime.h>
#include <hip/hip_bf16.h>

typedef __attribute__((ext_vector_type(8))) short short8;
typedef __attribute__((ext_vector_type(4))) float floatx4;
typedef __attribute__((ext_vector_type(4))) int intx4;

__device__ __forceinline__ unsigned short f2bf(float x) {
    union { float f; unsigned u; } v; v.f = x;
    unsigned r = v.u + 0x7fffu + ((v.u >> 16) & 1u);   // RNE; inputs here are never NaN
    return (unsigned short)(r >> 16);
}

__device__ __forceinline__ short8 pack8(float4 a, float4 b) {
    short8 s;
    s[0] = (short)f2bf(a.x); s[1] = (short)f2bf(a.y);
    s[2] = (short)f2bf(a.z); s[3] = (short)f2bf(a.w);
    s[4] = (short)f2bf(b.x); s[5] = (short)f2bf(b.y);
    s[6] = (short)f2bf(b.z); s[7] = (short)f2bf(b.w);
    return s;
}

__device__ __forceinline__ float fast_tanh(float x) {
    float e = __expf(2.0f * x);
    return 1.0f - 2.0f * __builtin_amdgcn_rcpf(e + 1.0f);
}

// ---------------------------------------------------------------------------
// Projection as MFMA GEMM (round-0 proven version, restored).  Output in
// PRE-FRAGMENTED TILE LAYOUT: frag[b][stile=s/16][kchunk=ch/32][lane][8],
// ch = h*64+e.  ~10 us, near its ~8 us HBM floor.
// ---------------------------------------------------------------------------
__global__ __launch_bounds__(256) void proj_kernel(
    const float* __restrict__ qin, const float* __restrict__ kin,
    const float* __restrict__ Wq, const float* __restrict__ bq,
    const float* __restrict__ Wk, const float* __restrict__ bk,
    const float* __restrict__ Wc,
    unsigned short* __restrict__ qt, unsigned short* __restrict__ kt)
{
    __shared__ unsigned short scr[4][16 * 72];
    const int which = blockIdx.y;             // 0 = q, 1 = k
    const float* in  = which ? kin : qin;
    const float* W   = which ? Wk  : Wq;
    const float* bi  = which ? bk  : bq;
    unsigned short* out = which ? kt : qt;

    const int tid  = threadIdx.x;
    const int lane = tid & 63;
    const int w    = tid >> 6;
    const int ln   = lane & 15;
    const int g    = lane >> 4;

    short8 wf[4][2];
    #pragma unroll
    for (int c = 0; c < 4; ++c)
        #pragma unroll
        for (int t = 0; t < 2; ++t) {
            const float* p = W + (c * 16 + ln) * 64 + t * 32 + (g << 3);
            wf[c][t] = pack8(*(const float4*)p, *(const float4*)(p + 4));
        }
    float be[4];
    #pragma unroll
    for (int c = 0; c < 4; ++c) be[c] = bi[c * 16 + ln];

    const int rb = blockIdx.x << 6;           // block's 64 rows: same (b,h)
    const int b  = rb >> 14;
    const int h  = (rb >> 10) & 15;
    const float sc = which ? 1.0f : Wc[h];

    const int r0 = rb + (w << 4);             // this wave's 16 rows (one s-tile)
    const int s0 = (rb & 1023) + (w << 4);
    floatx4 acc[4] = {{0,0,0,0},{0,0,0,0},{0,0,0,0},{0,0,0,0}};
    #pragma unroll
    for (int t = 0; t < 2; ++t) {
        const float* p = in + (size_t)(r0 + ln) * 64 + t * 32 + (g << 3);
        short8 af = pack8(*(const float4*)p, *(const float4*)(p + 4));
        #pragma unroll
        for (int c = 0; c < 4; ++c)
            acc[c] = __builtin_amdgcn_mfma_f32_16x16x32_bf16(af, wf[c][t], acc[c], 0, 0, 0);
    }

    // C/D: col e = c*16+ln, row m = g*4+r.  Stage tile (16 s x 64 e) in LDS.
    unsigned short* s_scr = scr[w];
    #pragma unroll
    for (int c = 0; c < 4; ++c)
        #pragma unroll
        for (int r = 0; r < 4; ++r)
            s_scr[((g << 2) + r) * 72 + (c << 4) + ln] =
                f2bf(fast_tanh(acc[c][r] + be[c]) * sc);
    __syncthreads();

    const int itg = (b << 6) + (s0 >> 4);
    unsigned short* obase = out + ((size_t)(itg * 32 + h * 2) << 9) + (lane << 3);
    #pragma unroll
    for (int e2 = 0; e2 < 2; ++e2) {          // kchunk = h*2 + e2
        short8 v = *(const short8*)&s_scr[ln * 72 + (e2 << 5) + (g << 3)];
        *(short8*)(obase + (e2 << 9)) = v;
    }
}

// ---------------------------------------------------------------------------
// attn, round-5: 2 BLOCKS/CU for phase-level concurrency.
// Round-4 counters (first direct attn reading): 45 us, everything idle
// (HBM 17%, Mfma 7%, Occ 37%) and WRITE 31 MB vs 16.8 ideal (NT partial-line
// RMW).  Diagnosis: 1 block/CU = strict phase chain; every latency stall
// gates all 16 waves.  Fix: 512 blocks x 512 threads (16 q-rows x 512
// k-cols, LDS 66.5 KB -> 2 blocks/CU); two async blocks/CU overlap each
// other's barrier/latency phases.  Out stores now regular (L2 write-back,
// full lines).  In-block A-proj reverted (cost ~5 us serial).  Proven parts
// kept: qt/kt frag precompute, T14 mask split, k-split pair rendezvous
// (sibling = id^8, same XCD), depth-2 register prefetch rings.
// ---------------------------------------------------------------------------
#define RVMAGIC 0x9E3779B97F4A7C15ULL

__global__ __launch_bounds__(512, 4) void attn_kernel(
    const unsigned short* __restrict__ qt, const unsigned short* __restrict__ kt,
    const int* __restrict__ mask, float* __restrict__ out,
    float* __restrict__ psums, unsigned long long* __restrict__ pflags)
{
    __shared__ __align__(16) unsigned short Al[16384];   // 32 KB: 1 s-tile, frag order
    __shared__ __align__(16) int Ml[16 * 516];           // 33 KB mask tile, padded rows
    __shared__ float red[8][16];
    __shared__ float tot0[16], tot1[16];

    const int tid  = threadIdx.x;
    const int lane = tid & 63;
    const int w    = tid >> 6;                // 0..7
    const int ln   = lane & 15;
    const int g    = lane >> 4;

    const int id  = blockIdx.x;               // 0..511
    const int b   = id & 3;
    const int qlo = (id >> 2) & 1;
    const int ks  = (id >> 3) & 1;            // k-half; sibling = id ^ 8 (same XCD)
    const int qs  = ((id >> 4) << 1) | qlo;   // 0..63: 16-row q tile
    const int i0  = qs << 4;
    const int slot = (((b << 6) + qs) << 1) + ks;
    const int sib  = slot ^ 1;

    // ---- mask: issue loads now (NT), write to LDS late (T14 split) ----
    const int* mSrc = mask + ((size_t)((b << 10) + i0) << 10) + (ks << 9);
    intx4 mreg[4];
    #pragma unroll
    for (int rr = 0; rr < 4; ++rr) {
        const int idx = (rr << 9) + tid;      // int4 chunk id, 128 per row, 2048 total
        mreg[rr] = __builtin_nontemporal_load(
            (const intx4*)(mSrc + ((idx >> 7) << 10) + ((idx & 127) << 2)));
    }

    // ---- B prologue: depth-2 ring x 4 streams (global; overlaps staging) ----
    const unsigned short* bP = kt + ((size_t)((b << 6) + (ks << 5) + (w << 2)) << 14) + (lane << 3);
    short8 bv[2][4];
    #pragma unroll
    for (int p = 0; p < 2; ++p)
        #pragma unroll
        for (int nt = 0; nt < 4; ++nt)
            bv[p][nt] = *(const short8*)(bP + (nt << 14) + (p << 9));

    // ---- stage A: one 16-row s-tile, 32 KB linear copy ----
    const unsigned short* aSrc = qt + ((size_t)((b << 6) + qs) << 14);
    #pragma unroll
    for (int rr = 0; rr < 4; ++rr) {
        const int idx = (rr << 9) + tid;      // 8-short chunk id, 2048 total
        *(short8*)&Al[idx << 3] = *(const short8*)(aSrc + ((size_t)idx << 3));
    }
    // ---- mask write-late ----
    #pragma unroll
    for (int rr = 0; rr < 4; ++rr) {
        const int idx = (rr << 9) + tid;
        *(intx4*)&Ml[(idx >> 7) * 516 + ((idx & 127) << 2)] = mreg[rr];
    }
    __syncthreads();

    const unsigned short* aL = &Al[lane << 3];
    short8 av[2];
    av[0] = *(const short8*)(aL);
    av[1] = *(const short8*)(aL + (1 << 9));

    floatx4 acc[4] = {{0,0,0,0},{0,0,0,0},{0,0,0,0},{0,0,0,0}};

    // main loop: 30 iters with refills at +2, then 2-iter tail
    for (int kb = 0; kb < 30; kb += 2) {
        #pragma unroll
        for (int s = 0; s < 2; ++s) {
            const int kc = kb + s;
            acc[0] = __builtin_amdgcn_mfma_f32_16x16x32_bf16(av[s], bv[s][0], acc[0], 0, 0, 0);
            acc[1] = __builtin_amdgcn_mfma_f32_16x16x32_bf16(av[s], bv[s][1], acc[1], 0, 0, 0);
            acc[2] = __builtin_amdgcn_mfma_f32_16x16x32_bf16(av[s], bv[s][2], acc[2], 0, 0, 0);
            acc[3] = __builtin_amdgcn_mfma_f32_16x16x32_bf16(av[s], bv[s][3], acc[3], 0, 0, 0);
            const int o2 = (kc + 2) << 9;
            bv[s][0] = *(const short8*)(bP + o2);
            bv[s][1] = *(const short8*)(bP + (1 << 14) + o2);
            bv[s][2] = *(const short8*)(bP + (2 << 14) + o2);
            bv[s][3] = *(const short8*)(bP + (3 << 14) + o2);
            av[s] = *(const short8*)(aL + o2);
        }
    }
    #pragma unroll
    for (int s = 0; s < 2; ++s) {             // tail: kc = 30,31, no refills
        acc[0] = __builtin_amdgcn_mfma_f32_16x16x32_bf16(av[s], bv[s][0], acc[0], 0, 0, 0);
        acc[1] = __builtin_amdgcn_mfma_f32_16x16x32_bf16(av[s], bv[s][1], acc[1], 0, 0, 0);
        acc[2] = __builtin_amdgcn_mfma_f32_16x16x32_bf16(av[s], bv[s][2], acc[2], 0, 0, 0);
        acc[3] = __builtin_amdgcn_mfma_f32_16x16x32_bf16(av[s], bv[s][3], acc[3], 0, 0, 0);
    }

    // epilogue: masked exp; C/D: row = g*4+r, col = w*64 + nt*16 + ln
    float psum[4] = {0.f, 0.f, 0.f, 0.f};
    #pragma unroll
    for (int nt = 0; nt < 4; ++nt) {
        const int j = (w << 6) + (nt << 4) + ln;
        #pragma unroll
        for (int r = 0; r < 4; ++r) {
            const int mv = Ml[((g << 2) + r) * 516 + j];
            float e = mv ? __expf(acc[nt][r]) : 0.0f;
            acc[nt][r] = e;
            psum[r] += e;
        }
    }
    #pragma unroll
    for (int off = 1; off < 16; off <<= 1)
        #pragma unroll
        for (int r = 0; r < 4; ++r) psum[r] += __shfl_xor(psum[r], off);
    if (ln == 0) {
        #pragma unroll
        for (int r = 0; r < 4; ++r) red[w][(g << 2) + r] = psum[r];
    }
    __syncthreads();

    // block-half row sums -> publish; rendezvous with sibling (other k-half)
    if (tid < 16) {
        float s = 0.f;
        #pragma unroll
        for (int ww = 0; ww < 8; ++ww) s += red[ww][tid];
        tot0[tid] = s;
        __hip_atomic_store(&psums[(slot << 4) + tid], s,
                           __ATOMIC_RELAXED, __HIP_MEMORY_SCOPE_AGENT);
    }
    __syncthreads();                          // all sums stores drained
    if (tid == 0) {
        __threadfence();                      // device-scope release
        __hip_atomic_store(&pflags[slot], RVMAGIC,
                           __ATOMIC_RELAXED, __HIP_MEMORY_SCOPE_AGENT);
        int guard = 0;
        while (__hip_atomic_load(&pflags[sib], __ATOMIC_RELAXED,
                                 __HIP_MEMORY_SCOPE_AGENT) != RVMAGIC) {
            __builtin_amdgcn_s_sleep(2);
            if (++guard > (1 << 22)) break;   // failsafe: never hang the bench
        }
        __threadfence();                      // device-scope acquire
    }
    __syncthreads();
    if (tid < 16)
        tot1[tid] = __hip_atomic_load(&psums[(sib << 4) + tid],
                                      __ATOMIC_RELAXED, __HIP_MEMORY_SCOPE_AGENT);
    __syncthreads();

    // normalize with combined denominators; REGULAR stores (L2 assembles
    // full lines across the block's waves -> no HBM RMW amplification)
    float* ob = out + ((size_t)((b << 10) + i0) << 10) + (ks << 9);
    #pragma unroll
    for (int r = 0; r < 4; ++r) {
        const int row = (g << 2) + r;
        const float inv = 1.0f / (tot0[row] + tot1[row]);
        #pragma unroll
        for (int nt = 0; nt < 4; ++nt) {
            const int j = (w << 6) + (nt << 4) + ln;
            ob[((size_t)row << 10) + j] = acc[nt][r] * inv;
        }
    }
}

extern "C" void kernel_launch(void* const* d_in, const int* in_sizes, int n_in,
                              void* d_out, int out_size, void* d_ws, size_t ws_size,
                              hipStream_t stream)
{
    const float* query = (const float*)d_in[0];
    const float* key   = (const float*)d_in[1];
    const int*   mask  = (const int*)d_in[2];
    const float* Wq    = (const float*)d_in[3];
    const float* bq    = (const float*)d_in[4];
    const float* Wk    = (const float*)d_in[5];
    const float* bk    = (const float*)d_in[6];
    const float* Wc    = (const float*)d_in[7];
    // d_in[8] (bc) intentionally unused: constant shift cancels in softmax.

    float* out = (float*)d_out;
    unsigned short* qt = (unsigned short*)d_ws;                 // 8 MiB bf16 (frag layout)
    unsigned short* kt = qt + (size_t)4 * 1024 * 1024;          // 8 MiB bf16 (frag layout)
    char* extra = (char*)d_ws + (size_t)16 * 1024 * 1024;
    float* psums = (float*)extra;                               // 512 slots x 16 floats = 32 KB
    unsigned long long* pflags = (unsigned long long*)(extra + 32 * 1024);  // 512 x 8 B

    proj_kernel<<<dim3(1024, 2), 256, 0, stream>>>(query, key, Wq, bq, Wk, bk, Wc, qt, kt);
    attn_kernel<<<512, 512, 0, stream>>>(qt, kt, mask, out, psums, pflags);
}

// Round 7
// 131.938 us; speedup vs baseline: 1.2495x; 1.2495x over previous
//
#include <hip/hip_runtime.h>
#include <hip/hip_bf16.h>

typedef __attribute__((ext_vector_type(8))) short short8;
typedef __attribute__((ext_vector_type(4))) float floatx4;
typedef __attribute__((ext_vector_type(4))) int intx4;

__device__ __forceinline__ unsigned short f2bf(float x) {
    union { float f; unsigned u; } v; v.f = x;
    unsigned r = v.u + 0x7fffu + ((v.u >> 16) & 1u);   // RNE; inputs here are never NaN
    return (unsigned short)(r >> 16);
}

__device__ __forceinline__ short8 pack8(float4 a, float4 b) {
    short8 s;
    s[0] = (short)f2bf(a.x); s[1] = (short)f2bf(a.y);
    s[2] = (short)f2bf(a.z); s[3] = (short)f2bf(a.w);
    s[4] = (short)f2bf(b.x); s[5] = (short)f2bf(b.y);
    s[6] = (short)f2bf(b.z); s[7] = (short)f2bf(b.w);
    return s;
}

__device__ __forceinline__ float fast_tanh(float x) {
    float e = __expf(2.0f * x);
    return 1.0f - 2.0f * __builtin_amdgcn_rcpf(e + 1.0f);
}

// ---------------------------------------------------------------------------
// Projection as MFMA GEMM (proven round-0/1 version, byte-identical).
// Output in PRE-FRAGMENTED TILE LAYOUT:
//   frag[b][stile=s/16][kchunk=ch/32][lane][8shorts], ch = h*64+e.
// ---------------------------------------------------------------------------
__global__ __launch_bounds__(256) void proj_kernel(
    const float* __restrict__ qin, const float* __restrict__ kin,
    const float* __restrict__ Wq, const float* __restrict__ bq,
    const float* __restrict__ Wk, const float* __restrict__ bk,
    const float* __restrict__ Wc,
    unsigned short* __restrict__ qt, unsigned short* __restrict__ kt)
{
    __shared__ unsigned short scr[4][16 * 72];
    const int which = blockIdx.y;             // 0 = q, 1 = k
    const float* in  = which ? kin : qin;
    const float* W   = which ? Wk  : Wq;
    const float* bi  = which ? bk  : bq;
    unsigned short* out = which ? kt : qt;

    const int tid  = threadIdx.x;
    const int lane = tid & 63;
    const int w    = tid >> 6;
    const int ln   = lane & 15;
    const int g    = lane >> 4;

    short8 wf[4][2];
    #pragma unroll
    for (int c = 0; c < 4; ++c)
        #pragma unroll
        for (int t = 0; t < 2; ++t) {
            const float* p = W + (c * 16 + ln) * 64 + t * 32 + (g << 3);
            wf[c][t] = pack8(*(const float4*)p, *(const float4*)(p + 4));
        }
    float be[4];
    #pragma unroll
    for (int c = 0; c < 4; ++c) be[c] = bi[c * 16 + ln];

    const int rb = blockIdx.x << 6;           // block's 64 rows: same (b,h)
    const int b  = rb >> 14;
    const int h  = (rb >> 10) & 15;
    const float sc = which ? 1.0f : Wc[h];

    const int r0 = rb + (w << 4);             // this wave's 16 rows (one s-tile)
    const int s0 = (rb & 1023) + (w << 4);
    floatx4 acc[4] = {{0,0,0,0},{0,0,0,0},{0,0,0,0},{0,0,0,0}};
    #pragma unroll
    for (int t = 0; t < 2; ++t) {
        const float* p = in + (size_t)(r0 + ln) * 64 + t * 32 + (g << 3);
        short8 af = pack8(*(const float4*)p, *(const float4*)(p + 4));
        #pragma unroll
        for (int c = 0; c < 4; ++c)
            acc[c] = __builtin_amdgcn_mfma_f32_16x16x32_bf16(af, wf[c][t], acc[c], 0, 0, 0);
    }

    // C/D: col e = c*16+ln, row m = g*4+r.  Stage tile (16 s x 64 e) in LDS.
    unsigned short* s_scr = scr[w];
    #pragma unroll
    for (int c = 0; c < 4; ++c)
        #pragma unroll
        for (int r = 0; r < 4; ++r)
            s_scr[((g << 2) + r) * 72 + (c << 4) + ln] =
                f2bf(fast_tanh(acc[c][r] + be[c]) * sc);
    __syncthreads();

    const int itg = (b << 6) + (s0 >> 4);
    unsigned short* obase = out + ((size_t)(itg * 32 + h * 2) << 9) + (lane << 3);
    #pragma unroll
    for (int e2 = 0; e2 < 2; ++e2) {          // kchunk = h*2 + e2
        short8 v = *(const short8*)&s_scr[ln * 72 + (e2 << 5) + (g << 3)];
        *(short8*)(obase + (e2 << 9)) = v;
    }
}

// ---------------------------------------------------------------------------
// attn, round-7 (= round-6 resubmit; round-6 was an infra failure, no data).
// Round-1 kernel (best measured, 136.9 us total) with the device-scope
// __threadfence()s DELETED from the pair rendezvous.
// Theory: on CDNA4 a device-scope fence is heavyweight cache maintenance
// (L2 writeback/invalidate class), executed 2x per block while all other
// waves sit at a barrier — the hidden cost common to every measured attn
// (45-50 us with all pipes <17% busy) and to round-3's 191 us fused blowup.
// The fences are unnecessary here: siblings (id^8) share an XCD, L1 is
// write-through, relaxed atomics (sc0) hit L2 directly, and the barrier
// before the flag store drains vmcnt(0) so psums are complete in L2 before
// the flag publishes.  Second change: regular out stores (round-5 proved
// NT scalar stores amplify WRITE 31 MB vs 16.4 ideal).
// Defensive tweaks this resubmit: spin guard 1<<20 (~50 ms worst case),
// longer s_sleep while spinning.
// ---------------------------------------------------------------------------
#define RVMAGIC 0x9E3779B97F4A7C15ULL

__global__ __launch_bounds__(1024, 4) void attn_kernel(
    const unsigned short* __restrict__ qt, const unsigned short* __restrict__ kt,
    const int* __restrict__ mask, float* __restrict__ out,
    float* __restrict__ psums, unsigned long long* __restrict__ pflags)
{
    __shared__ __align__(16) unsigned short Al[32768];   // 64 KB: 2 s-tiles, frag order
    __shared__ __align__(16) int Ml[32 * 516];           // ~66 KB mask tile, padded rows
    __shared__ float red[16][32];
    __shared__ float tot0[32], tot1[32];

    const int tid  = threadIdx.x;
    const int lane = tid & 63;
    const int w    = tid >> 6;                // 0..15
    const int ln   = lane & 15;
    const int g    = lane >> 4;

    const int id  = blockIdx.x;
    const int b   = id & 3;
    const int qlo = (id >> 2) & 1;
    const int ks  = (id >> 3) & 1;            // k-half; sibling = id ^ 8 (same XCD)
    const int qs  = ((id >> 4) << 1) | qlo;   // 0..31: 32-row q supertile
    const int i0  = qs << 5;
    const int slot = (((b << 5) + qs) << 1) + ks;
    const int sib  = slot ^ 1;

    // ---- stage A: two consecutive 16-row tiles, 64 KB linear copy ----
    const unsigned short* aSrc = qt + ((size_t)((b << 6) + (qs << 1)) << 14);
    #pragma unroll
    for (int rr = 0; rr < 4; ++rr) {
        const int idx = (rr << 10) + tid;     // 8-short chunk id
        *(short8*)&Al[idx << 3] = *(const short8*)(aSrc + ((size_t)idx << 3));
    }
    // ---- stage mask: 32 rows x 512 ints (this k-half), row stride 516 ----
    const int* mSrc = mask + ((size_t)((b << 10) + i0) << 10) + (ks << 9);
    #pragma unroll
    for (int rr = 0; rr < 4; ++rr) {
        const int idx = (rr << 10) + tid;     // int4 chunk id, 128 per row
        const int li  = idx >> 7;
        const int cj  = idx & 127;
        intx4 mv = __builtin_nontemporal_load((const intx4*)(mSrc + (li << 10) + (cj << 2)));
        *(intx4*)&Ml[li * 516 + (cj << 2)] = mv;
    }
    __syncthreads();

    const unsigned short* bP = kt + ((size_t)((b << 6) + (ks << 5) + (w << 1)) << 14) + (lane << 3);
    const unsigned short* a0 = &Al[lane << 3];
    const unsigned short* a1 = &Al[16384 + (lane << 3)];

    floatx4 acc[2][2] = {{{0,0,0,0},{0,0,0,0}},{{0,0,0,0},{0,0,0,0}}};

    short8 av0 = *(const short8*)a0;
    short8 av1 = *(const short8*)a1;
    short8 bv0 = *(const short8*)bP;
    short8 bv1 = *(const short8*)(bP + (1 << 14));

    for (int kc = 1; kc < 32; ++kc) {
        const int o = kc << 9;                // chunk stride = 512 shorts = 1 KB
        short8 an0 = *(const short8*)(a0 + o);            // ds_read_b128
        short8 an1 = *(const short8*)(a1 + o);
        short8 bn0 = *(const short8*)(bP + o);
        short8 bn1 = *(const short8*)(bP + (1 << 14) + o);
        acc[0][0] = __builtin_amdgcn_mfma_f32_16x16x32_bf16(av0, bv0, acc[0][0], 0, 0, 0);
        acc[0][1] = __builtin_amdgcn_mfma_f32_16x16x32_bf16(av0, bv1, acc[0][1], 0, 0, 0);
        acc[1][0] = __builtin_amdgcn_mfma_f32_16x16x32_bf16(av1, bv0, acc[1][0], 0, 0, 0);
        acc[1][1] = __builtin_amdgcn_mfma_f32_16x16x32_bf16(av1, bv1, acc[1][1], 0, 0, 0);
        av0 = an0; av1 = an1; bv0 = bn0; bv1 = bn1;
    }
    acc[0][0] = __builtin_amdgcn_mfma_f32_16x16x32_bf16(av0, bv0, acc[0][0], 0, 0, 0);
    acc[0][1] = __builtin_amdgcn_mfma_f32_16x16x32_bf16(av0, bv1, acc[0][1], 0, 0, 0);
    acc[1][0] = __builtin_amdgcn_mfma_f32_16x16x32_bf16(av1, bv0, acc[1][0], 0, 0, 0);
    acc[1][1] = __builtin_amdgcn_mfma_f32_16x16x32_bf16(av1, bv1, acc[1][1], 0, 0, 0);

    // epilogue: masked exp; C/D: row = st*16 + g*4 + r, col = w*32 + nt*16 + ln
    float psum[2][4] = {{0.f,0.f,0.f,0.f},{0.f,0.f,0.f,0.f}};
    #pragma unroll
    for (int st = 0; st < 2; ++st)
        #pragma unroll
        for (int nt = 0; nt < 2; ++nt) {
            const int j = (w << 5) + (nt << 4) + ln;
            #pragma unroll
            for (int r = 0; r < 4; ++r) {
                const int mv = Ml[((st << 4) + (g << 2) + r) * 516 + j];
                float e = mv ? __expf(acc[st][nt][r]) : 0.0f;
                acc[st][nt][r] = e;
                psum[st][r] += e;
            }
        }
    #pragma unroll
    for (int off = 1; off < 16; off <<= 1)
        #pragma unroll
        for (int st = 0; st < 2; ++st)
            #pragma unroll
            for (int r = 0; r < 4; ++r) psum[st][r] += __shfl_xor(psum[st][r], off);
    if (ln == 0) {
        #pragma unroll
        for (int st = 0; st < 2; ++st)
            #pragma unroll
            for (int r = 0; r < 4; ++r)
                red[w][(st << 4) + (g << 2) + r] = psum[st][r];
    }
    __syncthreads();

    // block-half row sums -> publish; rendezvous with sibling (other k-half).
    // Ordering WITHOUT device-scope fences: psums atomic stores (sc0 -> L2)
    // are drained by the vmcnt(0) the compiler emits before the barrier; the
    // flag store is program-ordered after the barrier; the sibling reads
    // flag and psums via sc0 atomic loads (L2, same XCD).  No __threadfence.
    if (tid < 32) {
        float s = 0.f;
        #pragma unroll
        for (int ww = 0; ww < 16; ++ww) s += red[ww][tid];
        tot0[tid] = s;
        __hip_atomic_store(&psums[(slot << 5) + tid], s,
                           __ATOMIC_RELAXED, __HIP_MEMORY_SCOPE_AGENT);
    }
    __syncthreads();                          // vmcnt(0) drain: psums visible in L2
    if (tid == 0) {
        asm volatile("s_waitcnt vmcnt(0)" ::: "memory");   // belt-and-braces
        __hip_atomic_store(&pflags[slot], RVMAGIC,
                           __ATOMIC_RELAXED, __HIP_MEMORY_SCOPE_AGENT);
        int guard = 0;
        while (__hip_atomic_load(&pflags[sib], __ATOMIC_RELAXED,
                                 __HIP_MEMORY_SCOPE_AGENT) != RVMAGIC) {
            __builtin_amdgcn_s_sleep(8);
            if (++guard > (1 << 20)) break;   // failsafe ~50 ms: never hang
        }
    }
    __syncthreads();
    if (tid < 32)
        tot1[tid] = __hip_atomic_load(&psums[(sib << 5) + tid],
                                      __ATOMIC_RELAXED, __HIP_MEMORY_SCOPE_AGENT);
    __syncthreads();

    // normalize with combined denominators; REGULAR stores (L2 write-back
    // assembles full lines -> no HBM RMW amplification; round-5 verified)
    float* ob = out + ((size_t)((b << 10) + i0) << 10) + (ks << 9);
    #pragma unroll
    for (int st = 0; st < 2; ++st) {
        #pragma unroll
        for (int r = 0; r < 4; ++r) {
            const int row = (st << 4) + (g << 2) + r;
            const float inv = 1.0f / (tot0[row] + tot1[row]);
            #pragma unroll
            for (int nt = 0; nt < 2; ++nt) {
                const int j = (w << 5) + (nt << 4) + ln;
                ob[((size_t)row << 10) + j] = acc[st][nt][r] * inv;
            }
        }
    }
}

extern "C" void kernel_launch(void* const* d_in, const int* in_sizes, int n_in,
                              void* d_out, int out_size, void* d_ws, size_t ws_size,
                              hipStream_t stream)
{
    const float* query = (const float*)d_in[0];
    const float* key   = (const float*)d_in[1];
    const int*   mask  = (const int*)d_in[2];
    const float* Wq    = (const float*)d_in[3];
    const float* bq    = (const float*)d_in[4];
    const float* Wk    = (const float*)d_in[5];
    const float* bk    = (const float*)d_in[6];
    const float* Wc    = (const float*)d_in[7];
    // d_in[8] (bc) intentionally unused: constant shift cancels in softmax.

    float* out = (float*)d_out;
    unsigned short* qt = (unsigned short*)d_ws;                 // 8 MiB bf16 (frag layout)
    unsigned short* kt = qt + (size_t)4 * 1024 * 1024;          // 8 MiB bf16 (frag layout)
    char* extra = (char*)d_ws + (size_t)16 * 1024 * 1024;
    float* psums = (float*)extra;                               // 256 slots x 32 floats
    unsigned long long* pflags = (unsigned long long*)(extra + 32 * 1024);

    proj_kernel<<<dim3(1024, 2), 256, 0, stream>>>(query, key, Wq, bq, Wk, bk, Wc, qt, kt);
    attn_kernel<<<256, 1024, 0, stream>>>(qt, kt, mask, out, psums, pflags);
}